// Round 16
// baseline (291.347 us; speedup 1.0000x reference)
//
#include <hip/hip_runtime.h>

#define N_NODES 100000
#define N_EDGES 1600000
#define NB      1024
#define EPSF    1e-5f

#define SCHUNK 256
#define SNBLK ((N_NODES + SCHUNK - 1) / SCHUNK)   // 391

#define BUK_SH  7
#define NBUK    ((N_NODES + 127) >> 7)            // 782 buckets of 128 heads
#define EPB     6400
#define NBA     ((N_EDGES + EPB - 1) / EPB)       // 250 binning blocks
#define CAP     3072                              // LDS record cap per bucket

typedef float f32x4  __attribute__((ext_vector_type(4)));
typedef short bf16x8 __attribute__((ext_vector_type(8)));

__device__ __forceinline__ float bf2f(unsigned short u) {
    union { unsigned int i; float f; } v; v.i = ((unsigned int)u) << 16; return v.f;
}
__device__ __forceinline__ unsigned short f2bf(float f) {
    union { float ff; unsigned int i; } v; v.ff = f;
    unsigned int r = v.i + 0x7FFFu + ((v.i >> 16) & 1u);   // RNE
    return (unsigned short)(r >> 16);
}

// -------------- per-channel mean/var(ddof=1) -> scale/shift --------------
template<int C>
__global__ __launch_bounds__(256) void stats_kernel(const float* __restrict__ jet,
                                                    const float* __restrict__ g,
                                                    const float* __restrict__ b,
                                                    float* __restrict__ scale,
                                                    float* __restrict__ shift) {
    int c = blockIdx.x;
    int t = threadIdx.x;
    float s = 0.f, s2 = 0.f;
    for (int r = t; r < NB; r += 256) {
        float v = jet[r * C + c];
        s += v; s2 += v * v;
    }
    __shared__ float ls[256], ls2[256];
    ls[t] = s; ls2[t] = s2;
    __syncthreads();
    for (int ofs = 128; ofs > 0; ofs >>= 1) {
        if (t < ofs) { ls[t] += ls[t + ofs]; ls2[t] += ls2[t + ofs]; }
        __syncthreads();
    }
    if (t == 0) {
        float mean = ls[0] / (float)NB;
        float var  = (ls2[0] - (float)NB * mean * mean) / (float)(NB - 1);
        float sc   = g[c] / sqrtf(var + EPSF);
        scale[c] = sc;
        shift[c] = b[c] - mean * sc;
    }
}

// ---------------- count kernels ------------------------------------------
__global__ __launch_bounds__(256) void countI_kernel(const int* __restrict__ ind,
                                                     int* __restrict__ cntI) {
    int n = blockIdx.x * 256 + threadIdx.x;
    if (n < N_NODES) atomicAdd(&cntI[ind[n]], 1);
}

__global__ __launch_bounds__(256) void count_head_kernel(const int* __restrict__ head,
                                                         int* __restrict__ cnt) {
    int e = blockIdx.x * 256 + threadIdx.x;
    if (e < N_EDGES) atomicAdd(&cnt[head[e]], 1);
}

// ---- countB2: per-bucket totals via LDS hist + 1 global add per bucket --
__global__ __launch_bounds__(1024) void countB2_kernel(const int* __restrict__ head,
                                                       int* __restrict__ bcnt) {
    __shared__ int h[NBUK];
    int tid = threadIdx.x;
    int blk = blockIdx.x;
    for (int i = tid; i < NBUK; i += 1024) h[i] = 0;
    __syncthreads();
    int e0 = blk * EPB;
    for (int k = tid; k < EPB; k += 1024) {
        int e = e0 + k;
        if (e < N_EDGES) atomicAdd(&h[head[e] >> BUK_SH], 1);
    }
    __syncthreads();
    for (int i = tid; i < NBUK; i += 1024)
        if (h[i] > 0) atomicAdd(&bcnt[i], h[i]);
}

// ---------------- scans ---------------------------------------------------
__global__ __launch_bounds__(SCHUNK) void scanA_kernel(const int* __restrict__ cnt,
                                                       int* __restrict__ part, int n) {
    __shared__ int ls[SCHUNK];
    int t = threadIdx.x;
    int i = blockIdx.x * SCHUNK + t;
    ls[t] = (i < n) ? cnt[i] : 0;
    __syncthreads();
    for (int ofs = SCHUNK / 2; ofs > 0; ofs >>= 1) {
        if (t < ofs) ls[t] += ls[t + ofs];
        __syncthreads();
    }
    if (t == 0) part[blockIdx.x] = ls[0];
}

// single-block scan (n <= 1024); EXCLUSIVE prefix to out (and out2)
__global__ __launch_bounds__(1024) void scanB_kernel(const int* __restrict__ in,
                                                     int* __restrict__ out,
                                                     int* __restrict__ out2, int n) {
    __shared__ int ls[1024];
    int t = threadIdx.x;
    int v = (t < n) ? in[t] : 0;
    ls[t] = v;
    __syncthreads();
    for (int ofs = 1; ofs < 1024; ofs <<= 1) {
        int u = (t >= ofs) ? ls[t - ofs] : 0;
        __syncthreads();
        ls[t] += u;
        __syncthreads();
    }
    if (t < n) {
        int e = ls[t] - v;
        out[t] = e;
        if (out2) out2[t] = e;
    }
}

__global__ __launch_bounds__(SCHUNK) void scanC_kernel(const int* __restrict__ cnt,
                                                       const int* __restrict__ poff,
                                                       int* __restrict__ base,
                                                       int* __restrict__ cursor, int n) {
    __shared__ int ls[SCHUNK];
    int t = threadIdx.x;
    int i = blockIdx.x * SCHUNK + t;
    int v = (i < n) ? cnt[i] : 0;
    ls[t] = v;
    __syncthreads();
    for (int ofs = 1; ofs < SCHUNK; ofs <<= 1) {
        int u = (t >= ofs) ? ls[t - ofs] : 0;
        __syncthreads();
        ls[t] += u;
        __syncthreads();
    }
    if (i < n) {
        int bse = poff[blockIdx.x] + ls[t] - v;
        base[i] = bse;
        cursor[i] = bse;
    }
}

// ---- binC16b: decoupled chunk reservation + AoS 16B record scatter ------
// pass1: LDS hist; reserve chunk per bucket via one atomic; pass2 scatter.
__global__ __launch_bounds__(1024) void binC16b_kernel(const int* __restrict__ head,
                                                       const int* __restrict__ tail,
                                                       const float* __restrict__ pf,
                                                       int* __restrict__ bcur,
                                                       uint4* __restrict__ hb16) {
    __shared__ int lcnt[NBUK];
    __shared__ int lcur[NBUK];
    int tid = threadIdx.x;
    int blk = blockIdx.x;
    for (int i = tid; i < NBUK; i += 1024) lcnt[i] = 0;
    __syncthreads();
    int e0 = blk * EPB;
    for (int k = tid; k < EPB; k += 1024) {
        int e = e0 + k;
        if (e < N_EDGES) atomicAdd(&lcnt[head[e] >> BUK_SH], 1);
    }
    __syncthreads();
    for (int i = tid; i < NBUK; i += 1024)
        lcur[i] = (lcnt[i] > 0) ? atomicAdd(&bcur[i], lcnt[i]) : 0;
    __syncthreads();
    for (int k = tid; k < EPB; k += 1024) {
        int e = e0 + k;
        if (e < N_EDGES) {
            int hd = head[e];
            int b = hd >> BUK_SH;
            int slot = atomicAdd(&lcur[b], 1);
            float4 pv = ((const float4*)pf)[e];
            uint4 rec;
            rec.x = (unsigned)tail[e] | ((unsigned)(hd & 127) << 21);
            rec.y = (unsigned)f2bf(pv.x) | ((unsigned)f2bf(pv.y) << 16);
            rec.z = (unsigned)f2bf(pv.z) | ((unsigned)f2bf(pv.w) << 16);
            rec.w = 0u;
            hb16[slot] = rec;
        }
    }
}

// ---- sortGather: register-staged per-bucket CSR in LDS + fused gather ---
__global__ __launch_bounds__(512) void sortGather_kernel(const int* __restrict__ bbase,
                                                         const int* __restrict__ bcnt,
                                                         const uint4* __restrict__ hb16,
                                                         const unsigned short* __restrict__ hs,
                                                         unsigned short* __restrict__ agg) {
    __shared__ int hcnt[128];
    __shared__ int hbase[128];
    __shared__ int hcur[128];
    __shared__ int tail_l[CAP];        // 12KB
    __shared__ unsigned pf_l[2 * CAP]; // 24KB
    int tid = threadIdx.x;
    int b = blockIdx.x;
    int lo = bbase[b];
    int cnt = bcnt[b];
    int hi = lo + cnt;
    if (tid < 128) hcnt[tid] = 0;
    __syncthreads();

    int wv = tid >> 6, lane = tid & 63;
    int i = lane >> 1, half = lane & 1;

    if (cnt <= CAP) {
        uint4 r0, r1, r2, r3, r4, r5;
        int k0 = lo + tid;
        bool v0 = (k0 < hi),            v1 = (k0 + 512 < hi);
        bool v2 = (k0 + 1024 < hi),     v3 = (k0 + 1536 < hi);
        bool v4 = (k0 + 2048 < hi),     v5 = (k0 + 2560 < hi);
        if (v0) r0 = hb16[k0];
        if (v1) r1 = hb16[k0 + 512];
        if (v2) r2 = hb16[k0 + 1024];
        if (v3) r3 = hb16[k0 + 1536];
        if (v4) r4 = hb16[k0 + 2048];
        if (v5) r5 = hb16[k0 + 2560];
        if (v0) atomicAdd(&hcnt[r0.x >> 21], 1);
        if (v1) atomicAdd(&hcnt[r1.x >> 21], 1);
        if (v2) atomicAdd(&hcnt[r2.x >> 21], 1);
        if (v3) atomicAdd(&hcnt[r3.x >> 21], 1);
        if (v4) atomicAdd(&hcnt[r4.x >> 21], 1);
        if (v5) atomicAdd(&hcnt[r5.x >> 21], 1);
        __syncthreads();
        if (tid < 128) hbase[tid] = hcnt[tid];
        __syncthreads();
        for (int ofs = 1; ofs < 128; ofs <<= 1) {
            int v = (tid < 128 && tid >= ofs) ? hbase[tid - ofs] : 0;
            __syncthreads();
            if (tid < 128) hbase[tid] += v;
            __syncthreads();
        }
        if (tid < 128) {
            int bse = hbase[tid] - hcnt[tid];
            hbase[tid] = bse;
            hcur[tid] = bse;
        }
        __syncthreads();
        if (v0) { int s = atomicAdd(&hcur[r0.x >> 21], 1); tail_l[s] = (int)(r0.x & 0xFFFFFu); pf_l[2*s] = r0.y; pf_l[2*s+1] = r0.z; }
        if (v1) { int s = atomicAdd(&hcur[r1.x >> 21], 1); tail_l[s] = (int)(r1.x & 0xFFFFFu); pf_l[2*s] = r1.y; pf_l[2*s+1] = r1.z; }
        if (v2) { int s = atomicAdd(&hcur[r2.x >> 21], 1); tail_l[s] = (int)(r2.x & 0xFFFFFu); pf_l[2*s] = r2.y; pf_l[2*s+1] = r2.z; }
        if (v3) { int s = atomicAdd(&hcur[r3.x >> 21], 1); tail_l[s] = (int)(r3.x & 0xFFFFFu); pf_l[2*s] = r3.y; pf_l[2*s+1] = r3.z; }
        if (v4) { int s = atomicAdd(&hcur[r4.x >> 21], 1); tail_l[s] = (int)(r4.x & 0xFFFFFu); pf_l[2*s] = r4.y; pf_l[2*s+1] = r4.z; }
        if (v5) { int s = atomicAdd(&hcur[r5.x >> 21], 1); tail_l[s] = (int)(r5.x & 0xFFFFFu); pf_l[2*s] = r5.y; pf_l[2*s+1] = r5.z; }
        __syncthreads();
        // pass 3: gather from LDS, 8-deep unrolled hs loads
        for (int j = 0; j < 16; j++) {
            int h7 = (wv << 4) + j;
            int n = (b << BUK_SH) + h7;
            if (n >= N_NODES) break;
            int s0 = hbase[h7], c = hcnt[h7];
            float a0 = 0.f, a1 = 0.f;
            int k = 0;
            for (; k + 8 <= c; k += 8) {
                int t0 = tail_l[s0+k],   t1 = tail_l[s0+k+1];
                int t2 = tail_l[s0+k+2], t3 = tail_l[s0+k+3];
                int t4 = tail_l[s0+k+4], t5 = tail_l[s0+k+5];
                int t6 = tail_l[s0+k+6], t7 = tail_l[s0+k+7];
                float h0 = bf2f(hs[(size_t)t0 * 32 + i]);
                float h1 = bf2f(hs[(size_t)t1 * 32 + i]);
                float h2 = bf2f(hs[(size_t)t2 * 32 + i]);
                float h3 = bf2f(hs[(size_t)t3 * 32 + i]);
                float h4 = bf2f(hs[(size_t)t4 * 32 + i]);
                float h5 = bf2f(hs[(size_t)t5 * 32 + i]);
                float h6 = bf2f(hs[(size_t)t6 * 32 + i]);
                float h7f = bf2f(hs[(size_t)t7 * 32 + i]);
                unsigned u0 = pf_l[2*(s0+k)+half],   u1 = pf_l[2*(s0+k+1)+half];
                unsigned u2 = pf_l[2*(s0+k+2)+half], u3 = pf_l[2*(s0+k+3)+half];
                unsigned u4 = pf_l[2*(s0+k+4)+half], u5 = pf_l[2*(s0+k+5)+half];
                unsigned u6 = pf_l[2*(s0+k+6)+half], u7 = pf_l[2*(s0+k+7)+half];
                a0 += h0 * bf2f((unsigned short)(u0 & 0xFFFFu));
                a1 += h0 * bf2f((unsigned short)(u0 >> 16));
                a0 += h1 * bf2f((unsigned short)(u1 & 0xFFFFu));
                a1 += h1 * bf2f((unsigned short)(u1 >> 16));
                a0 += h2 * bf2f((unsigned short)(u2 & 0xFFFFu));
                a1 += h2 * bf2f((unsigned short)(u2 >> 16));
                a0 += h3 * bf2f((unsigned short)(u3 & 0xFFFFu));
                a1 += h3 * bf2f((unsigned short)(u3 >> 16));
                a0 += h4 * bf2f((unsigned short)(u4 & 0xFFFFu));
                a1 += h4 * bf2f((unsigned short)(u4 >> 16));
                a0 += h5 * bf2f((unsigned short)(u5 & 0xFFFFu));
                a1 += h5 * bf2f((unsigned short)(u5 >> 16));
                a0 += h6 * bf2f((unsigned short)(u6 & 0xFFFFu));
                a1 += h6 * bf2f((unsigned short)(u6 >> 16));
                a0 += h7f * bf2f((unsigned short)(u7 & 0xFFFFu));
                a1 += h7f * bf2f((unsigned short)(u7 >> 16));
            }
            for (; k < c; k++) {
                int t0 = tail_l[s0 + k];
                unsigned u0 = pf_l[2 * (s0 + k) + half];
                float h0 = bf2f(hs[(size_t)t0 * 32 + i]);
                a0 += h0 * bf2f((unsigned short)(u0 & 0xFFFFu));
                a1 += h0 * bf2f((unsigned short)(u0 >> 16));
            }
            unsigned pk = (unsigned)f2bf(a0) | ((unsigned)f2bf(a1) << 16);
            ((unsigned*)agg)[(size_t)n * 64 + lane] = pk;
        }
    } else {
        // overflow fallback: per-head redundant scan of the global window
        for (int j = 0; j < 16; j++) {
            int h7 = (wv << 4) + j;
            int n = (b << BUK_SH) + h7;
            if (n >= N_NODES) break;
            unsigned my = (unsigned)h7;
            float a0 = 0.f, a1 = 0.f;
            for (int k = lo; k < hi; k++) {
                uint4 rec = hb16[k];
                if ((rec.x >> 21) == my) {
                    unsigned u0 = (half == 0) ? rec.y : rec.z;
                    float h0 = bf2f(hs[(size_t)(rec.x & 0xFFFFFu) * 32 + i]);
                    a0 += h0 * bf2f((unsigned short)(u0 & 0xFFFFu));
                    a1 += h0 * bf2f((unsigned short)(u0 >> 16));
                }
            }
            unsigned pk = (unsigned)f2bf(a0) | ((unsigned)f2bf(a1) << 16);
            ((unsigned*)agg)[(size_t)n * 64 + lane] = pk;
        }
    }
}

// ---------------- legacy scatter (tier-2 fallback) -----------------------
__global__ __launch_bounds__(256) void escatterE_kernel(const int* __restrict__ head,
                                                        int* __restrict__ cursor,
                                                        int* __restrict__ eid) {
    int e = blockIdx.x * 256 + threadIdx.x;
    if (e >= N_EDGES) return;
    int slot = atomicAdd(&cursor[head[e]], 1);
    eid[slot] = e;
}

__global__ __launch_bounds__(256) void scatterI_kernel(const int* __restrict__ ind,
                                                       int* __restrict__ cursorI,
                                                       int* __restrict__ order) {
    int n = blockIdx.x * 256 + threadIdx.x;
    if (n < N_NODES) {
        int pos = atomicAdd(&cursorI[ind[n]], 1);
        order[pos] = n;
    }
}

// ---------- bucket jet (f32 input): jet[b,c] = sum x[n,c]*w[n] -----------
template<int C>
__global__ __launch_bounds__(256) void bucket_jet_kernel(const float* __restrict__ xx,
                                                         const float* __restrict__ w,
                                                         const int* __restrict__ order,
                                                         const int* __restrict__ baseI,
                                                         const int* __restrict__ cntI,
                                                         float* __restrict__ jet) {
    constexpr int G = 256 / C;
    __shared__ float red[256];
    int b = blockIdx.x;
    int g = threadIdx.x / C;
    int c = threadIdx.x % C;
    int s0 = baseI[b], m = cntI[b];
    float s = 0.f;
    for (int k = g; k < m; k += G) {
        int n = order[s0 + k];
        s += xx[(size_t)n * C + c] * w[n];
    }
    red[threadIdx.x] = s;
    __syncthreads();
    for (int half = G / 2; half > 0; half >>= 1) {
        if (g < half) red[g * C + c] += red[(g + half) * C + c];
        __syncthreads();
    }
    if (g == 0) jet[b * C + c] = red[c];
}

// ---------- bucket jet (bf16 input, C=128): uint-packed reads ------------
__global__ __launch_bounds__(256) void bucket_jet_bf128_kernel(const unsigned short* __restrict__ xx,
                                                               const float* __restrict__ w,
                                                               const int* __restrict__ order,
                                                               const int* __restrict__ baseI,
                                                               const int* __restrict__ cntI,
                                                               float* __restrict__ jet) {
    __shared__ float redA[256], redB[256];
    int b = blockIdx.x;
    int g  = threadIdx.x >> 6;     // 4 groups
    int c2 = threadIdx.x & 63;     // channel pair
    int s0 = baseI[b], m = cntI[b];
    float a0 = 0.f, a1 = 0.f;
    for (int k = g; k < m; k += 4) {
        int n = order[s0 + k];
        float wn = w[n];
        unsigned u = ((const unsigned*)xx)[(size_t)n * 64 + c2];
        a0 += bf2f((unsigned short)(u & 0xFFFFu)) * wn;
        a1 += bf2f((unsigned short)(u >> 16)) * wn;
    }
    redA[threadIdx.x] = a0; redB[threadIdx.x] = a1;
    __syncthreads();
    for (int half = 2; half > 0; half >>= 1) {
        if (g < half) {
            redA[g * 64 + c2] += redA[(g + half) * 64 + c2];
            redB[g * 64 + c2] += redB[(g + half) * 64 + c2];
        }
        __syncthreads();
    }
    if (g == 0) {
        jet[b * 128 + 2 * c2]     = redA[c2];
        jet[b * 128 + 2 * c2 + 1] = redB[c2];
    }
}

// --------- fused1 MFMA: hs = (relu(bn1(x)) @ W1^T) * w  (hs only) --------
#define TILE1 64
__global__ __launch_bounds__(256) void fused1_kernel(const float* __restrict__ x,
                                                     const float* __restrict__ w,
                                                     const float* __restrict__ scale,
                                                     const float* __restrict__ shift,
                                                     const float* __restrict__ W1,
                                                     unsigned short* __restrict__ hs) {
    __shared__ __align__(16) unsigned short xnb[TILE1 * 64];   // 8KB
    __shared__ __align__(16) unsigned short w1b[32 * 64];      // 4KB
    int tid = threadIdx.x;
    int n0  = blockIdx.x * TILE1;
    char* xnb_ = (char*)xnb; char* w1b_ = (char*)w1b;

    for (int idx = tid; idx < TILE1 * 8; idx += 256) {
        int r = idx >> 3, c0 = (idx & 7) << 3;
        int n = n0 + r;
        float4 vA = make_float4(0.f, 0.f, 0.f, 0.f), vB = vA;
        if (n < N_NODES) {
            vA = *(const float4*)&x[(size_t)n * 64 + c0];
            vB = *(const float4*)&x[(size_t)n * 64 + c0 + 4];
        }
        float4 scA = *(const float4*)&scale[c0], scB = *(const float4*)&scale[c0 + 4];
        float4 shA = *(const float4*)&shift[c0], shB = *(const float4*)&shift[c0 + 4];
        unsigned short na[8];
        na[0] = f2bf(fmaxf(fmaf(vA.x, scA.x, shA.x), 0.f));
        na[1] = f2bf(fmaxf(fmaf(vA.y, scA.y, shA.y), 0.f));
        na[2] = f2bf(fmaxf(fmaf(vA.z, scA.z, shA.z), 0.f));
        na[3] = f2bf(fmaxf(fmaf(vA.w, scA.w, shA.w), 0.f));
        na[4] = f2bf(fmaxf(fmaf(vB.x, scB.x, shB.x), 0.f));
        na[5] = f2bf(fmaxf(fmaf(vB.y, scB.y, shB.y), 0.f));
        na[6] = f2bf(fmaxf(fmaf(vB.z, scB.z, shB.z), 0.f));
        na[7] = f2bf(fmaxf(fmaf(vB.w, scB.w, shB.w), 0.f));
        int byte = ((r << 7) + ((idx & 7) << 4)) ^ ((r & 7) << 4);
        *(bf16x8*)(xnb_ + byte) = *(bf16x8*)na;
    }
    for (int idx = tid; idx < 32 * 8; idx += 256) {
        int r = idx >> 3, c0 = (idx & 7) << 3;
        float4 vA = *(const float4*)&W1[(size_t)r * 64 + c0];
        float4 vB = *(const float4*)&W1[(size_t)r * 64 + c0 + 4];
        unsigned short ua[8];
        ua[0] = f2bf(vA.x); ua[1] = f2bf(vA.y); ua[2] = f2bf(vA.z); ua[3] = f2bf(vA.w);
        ua[4] = f2bf(vB.x); ua[5] = f2bf(vB.y); ua[6] = f2bf(vB.z); ua[7] = f2bf(vB.w);
        int byte = ((r << 7) + ((idx & 7) << 4)) ^ ((r & 7) << 4);
        *(bf16x8*)(w1b_ + byte) = *(bf16x8*)ua;
    }
    __syncthreads();

    int wv   = tid >> 6;
    int lane = tid & 63;
    int l15  = lane & 15;
    int lhi  = lane >> 4;

    f32x4 acc[2];
    acc[0] = (f32x4){0.f, 0.f, 0.f, 0.f};
    acc[1] = (f32x4){0.f, 0.f, 0.f, 0.f};

#pragma unroll
    for (int ks = 0; ks < 2; ks++) {
        int rA = (wv << 4) + l15;
        int byteA = ((rA << 7) + (ks << 6) + (lhi << 4)) ^ ((rA & 7) << 4);
        bf16x8 a = *(const bf16x8*)(xnb_ + byteA);
#pragma unroll
        for (int cf = 0; cf < 2; cf++) {
            int rB = (cf << 4) + l15;
            int byteB = ((rB << 7) + (ks << 6) + (lhi << 4)) ^ ((rB & 7) << 4);
            bf16x8 b = *(const bf16x8*)(w1b_ + byteB);
            acc[cf] = __builtin_amdgcn_mfma_f32_16x16x32_bf16(a, b, acc[cf], 0, 0, 0);
        }
    }

#pragma unroll
    for (int cf = 0; cf < 2; cf++) {
        int co = (cf << 4) + l15;
#pragma unroll
        for (int j = 0; j < 4; j++) {
            int n = n0 + (wv << 4) + (lhi << 2) + j;
            if (n < N_NODES) hs[(size_t)n * 32 + co] = f2bf(acc[cf][j] * w[n]);
        }
    }
}

// ---------- gather (tier-2 only): wave per node via eid ------------------
__global__ __launch_bounds__(256) void gather2_kernel(const int* __restrict__ base,
                                                      const int* __restrict__ cnt,
                                                      const int* __restrict__ eid,
                                                      const int* __restrict__ tail,
                                                      const float* __restrict__ pf,
                                                      const unsigned short* __restrict__ hs,
                                                      unsigned short* __restrict__ agg) {
    int n = blockIdx.x * 4 + (threadIdx.x >> 6);
    if (n >= N_NODES) return;
    int lane = threadIdx.x & 63;
    int i = lane >> 1;
    int half = lane & 1;
    int s0 = base[n], c = cnt[n];
    float a0 = 0.f, a1 = 0.f;
    for (int k = 0; k < c; k++) {
        int e0 = eid[s0 + k];
        int t0 = tail[e0];
        float2 p0 = *(const float2*)&pf[(size_t)e0 * 4 + half * 2];
        float h0 = bf2f(hs[(size_t)t0 * 32 + i]);
        a0 += h0 * p0.x; a1 += h0 * p0.y;
    }
    unsigned pk = (unsigned)f2bf(a0) | ((unsigned)f2bf(a1) << 16);
    ((unsigned*)agg)[(size_t)n * 64 + lane] = pk;
}

// -------- legacy atomic edge scatter (tier-3, f32 agg) -------------------
__global__ __launch_bounds__(256) void edge_kernel(const int* __restrict__ head,
                                                   const int* __restrict__ tail,
                                                   const float* __restrict__ pf,
                                                   const unsigned short* __restrict__ hs,
                                                   float* __restrict__ agg) {
    long long tid = (long long)blockIdx.x * 256 + threadIdx.x;
    if (tid >= (long long)N_EDGES * 128) return;
    int e = (int)(tid >> 7);
    int j = (int)(tid & 127);
    int i = j >> 2, t = j & 3;
    float v = bf2f(hs[(size_t)tail[e] * 32 + i]) * pf[(size_t)e * 4 + t];
    atomicAdd(&agg[(size_t)head[e] * 128 + j], v);
}

// ------- fused2 MFMA: y = relu(bn(x)) @ W^T, in-place safe ---------------
#define TILE2 64
template<int INBF, int OUTBF>
__global__ __launch_bounds__(256) void fused2_kernel(const void* __restrict__ xin_,
                                                     const float* __restrict__ scale,
                                                     const float* __restrict__ shift,
                                                     const float* __restrict__ W,
                                                     void* __restrict__ yout_) {
    __shared__ __align__(16) unsigned short xnb[TILE2 * 128];   // 16KB
    __shared__ __align__(16) unsigned short wb[128 * 128];      // 32KB
    int tid = threadIdx.x;
    int n0  = blockIdx.x * TILE2;
    char* xbase = (char*)xnb;
    char* wbase = (char*)wb;

    for (int idx = tid; idx < TILE2 * 16; idx += 256) {
        int r = idx >> 4;
        int c0 = (idx & 15) << 3;
        int n = n0 + r;
        float f[8];
        if (n < N_NODES) {
            if (INBF) {
                const unsigned short* xu = (const unsigned short*)xin_;
                uint4 U = *(const uint4*)(xu + (size_t)n * 128 + c0);
                f[0] = bf2f((unsigned short)(U.x & 0xFFFFu)); f[1] = bf2f((unsigned short)(U.x >> 16));
                f[2] = bf2f((unsigned short)(U.y & 0xFFFFu)); f[3] = bf2f((unsigned short)(U.y >> 16));
                f[4] = bf2f((unsigned short)(U.z & 0xFFFFu)); f[5] = bf2f((unsigned short)(U.z >> 16));
                f[6] = bf2f((unsigned short)(U.w & 0xFFFFu)); f[7] = bf2f((unsigned short)(U.w >> 16));
            } else {
                const float* xf = (const float*)xin_;
                float4 vA = *(const float4*)&xf[(size_t)n * 128 + c0];
                float4 vB = *(const float4*)&xf[(size_t)n * 128 + c0 + 4];
                f[0] = vA.x; f[1] = vA.y; f[2] = vA.z; f[3] = vA.w;
                f[4] = vB.x; f[5] = vB.y; f[6] = vB.z; f[7] = vB.w;
            }
        } else {
#pragma unroll
            for (int q = 0; q < 8; q++) f[q] = 0.f;
        }
        unsigned short ua[8];
#pragma unroll
        for (int q = 0; q < 8; q++)
            ua[q] = f2bf(fmaxf(fmaf(f[q], scale[c0 + q], shift[c0 + q]), 0.f));
        int byte = ((r << 8) + ((idx & 15) << 4)) ^ ((r & 7) << 4);
        *(bf16x8*)(xbase + byte) = *(bf16x8*)ua;
    }
    for (int idx = tid; idx < 128 * 16; idx += 256) {
        int r = idx >> 4;
        int c0 = (idx & 15) << 3;
        float4 vA = *(const float4*)&W[(size_t)r * 128 + c0];
        float4 vB = *(const float4*)&W[(size_t)r * 128 + c0 + 4];
        unsigned short ua[8];
        ua[0] = f2bf(vA.x); ua[1] = f2bf(vA.y); ua[2] = f2bf(vA.z); ua[3] = f2bf(vA.w);
        ua[4] = f2bf(vB.x); ua[5] = f2bf(vB.y); ua[6] = f2bf(vB.z); ua[7] = f2bf(vB.w);
        int byte = ((r << 8) + ((idx & 15) << 4)) ^ ((r & 7) << 4);
        *(bf16x8*)(wbase + byte) = *(bf16x8*)ua;
    }
    __syncthreads();

    int wv   = tid >> 6;
    int lane = tid & 63;
    int l15  = lane & 15;
    int lhi  = lane >> 4;

    f32x4 acc[8];
#pragma unroll
    for (int cf = 0; cf < 8; cf++) acc[cf] = (f32x4){0.f, 0.f, 0.f, 0.f};

#pragma unroll
    for (int ks = 0; ks < 4; ks++) {
        int rA = (wv << 4) + l15;
        int byteA = ((rA << 8) + (ks << 6) + (lhi << 4)) ^ ((rA & 7) << 4);
        bf16x8 a = *(const bf16x8*)(xbase + byteA);
#pragma unroll
        for (int cf = 0; cf < 8; cf++) {
            int rB = (cf << 4) + l15;
            int byteB = ((rB << 8) + (ks << 6) + (lhi << 4)) ^ ((rB & 7) << 4);
            bf16x8 b = *(const bf16x8*)(wbase + byteB);
            acc[cf] = __builtin_amdgcn_mfma_f32_16x16x32_bf16(a, b, acc[cf], 0, 0, 0);
        }
    }

#pragma unroll
    for (int cf = 0; cf < 8; cf++) {
        int col = (cf << 4) + l15;
#pragma unroll
        for (int j = 0; j < 4; j++) {
            int n = n0 + (wv << 4) + (lhi << 2) + j;
            if (n < N_NODES) {
                float v = acc[cf][j];
                if (OUTBF) ((unsigned short*)yout_)[(size_t)n * 128 + col] = f2bf(v);
                else       ((float*)yout_)[(size_t)n * 128 + col] = v;
            }
        }
    }
}

// ------- fused3 dual-GEMM: out = relu(bn3(h2)) @ W3^T + x @ Wsc^T --------
template<int INBF>
__global__ __launch_bounds__(256) void fused3_kernel(const void* __restrict__ h2_,
                                                     const float* __restrict__ x,
                                                     const float* __restrict__ scale,
                                                     const float* __restrict__ shift,
                                                     const float* __restrict__ Wsc,
                                                     const float* __restrict__ W3,
                                                     float* __restrict__ out) {
    __shared__ __align__(16) unsigned short xnb[TILE2 * 128];   // 16KB (h2 normed)
    __shared__ __align__(16) unsigned short xrb[TILE2 * 64];    // 8KB  (x raw)
    __shared__ __align__(16) unsigned short wb[128 * 128];      // 32KB (Wsc then W3)
    int tid = threadIdx.x;
    int n0  = blockIdx.x * TILE2;
    char* xbase = (char*)xnb;
    char* rbase = (char*)xrb;
    char* wbase = (char*)wb;

    for (int idx = tid; idx < TILE2 * 16; idx += 256) {
        int r = idx >> 4;
        int c0 = (idx & 15) << 3;
        int n = n0 + r;
        float f[8];
        if (n < N_NODES) {
            if (INBF) {
                const unsigned short* xu = (const unsigned short*)h2_;
                uint4 U = *(const uint4*)(xu + (size_t)n * 128 + c0);
                f[0] = bf2f((unsigned short)(U.x & 0xFFFFu)); f[1] = bf2f((unsigned short)(U.x >> 16));
                f[2] = bf2f((unsigned short)(U.y & 0xFFFFu)); f[3] = bf2f((unsigned short)(U.y >> 16));
                f[4] = bf2f((unsigned short)(U.z & 0xFFFFu)); f[5] = bf2f((unsigned short)(U.z >> 16));
                f[6] = bf2f((unsigned short)(U.w & 0xFFFFu)); f[7] = bf2f((unsigned short)(U.w >> 16));
            } else {
                const float* xf = (const float*)h2_;
                float4 vA = *(const float4*)&xf[(size_t)n * 128 + c0];
                float4 vB = *(const float4*)&xf[(size_t)n * 128 + c0 + 4];
                f[0] = vA.x; f[1] = vA.y; f[2] = vA.z; f[3] = vA.w;
                f[4] = vB.x; f[5] = vB.y; f[6] = vB.z; f[7] = vB.w;
            }
        } else {
#pragma unroll
            for (int q = 0; q < 8; q++) f[q] = 0.f;
        }
        unsigned short ua[8];
#pragma unroll
        for (int q = 0; q < 8; q++)
            ua[q] = f2bf(fmaxf(fmaf(f[q], scale[c0 + q], shift[c0 + q]), 0.f));
        int byte = ((r << 8) + ((idx & 15) << 4)) ^ ((r & 7) << 4);
        *(bf16x8*)(xbase + byte) = *(bf16x8*)ua;
    }
    for (int idx = tid; idx < TILE2 * 8; idx += 256) {
        int r = idx >> 3, c0 = (idx & 7) << 3;
        int n = n0 + r;
        float4 vA = make_float4(0.f, 0.f, 0.f, 0.f), vB = vA;
        if (n < N_NODES) {
            vA = *(const float4*)&x[(size_t)n * 64 + c0];
            vB = *(const float4*)&x[(size_t)n * 64 + c0 + 4];
        }
        unsigned short ua[8];
        ua[0] = f2bf(vA.x); ua[1] = f2bf(vA.y); ua[2] = f2bf(vA.z); ua[3] = f2bf(vA.w);
        ua[4] = f2bf(vB.x); ua[5] = f2bf(vB.y); ua[6] = f2bf(vB.z); ua[7] = f2bf(vB.w);
        int byte = ((r << 7) + ((idx & 7) << 4)) ^ ((r & 7) << 4);
        *(bf16x8*)(rbase + byte) = *(bf16x8*)ua;
    }
    for (int idx = tid; idx < 128 * 8; idx += 256) {
        int r = idx >> 3, c0 = (idx & 7) << 3;
        float4 vA = *(const float4*)&Wsc[(size_t)r * 64 + c0];
        float4 vB = *(const float4*)&Wsc[(size_t)r * 64 + c0 + 4];
        unsigned short ua[8];
        ua[0] = f2bf(vA.x); ua[1] = f2bf(vA.y); ua[2] = f2bf(vA.z); ua[3] = f2bf(vA.w);
        ua[4] = f2bf(vB.x); ua[5] = f2bf(vB.y); ua[6] = f2bf(vB.z); ua[7] = f2bf(vB.w);
        int byte = ((r << 7) + ((idx & 7) << 4)) ^ ((r & 7) << 4);
        *(bf16x8*)(wbase + byte) = *(bf16x8*)ua;
    }
    __syncthreads();

    int wv   = tid >> 6;
    int lane = tid & 63;
    int l15  = lane & 15;
    int lhi  = lane >> 4;

    f32x4 acc[8];
#pragma unroll
    for (int cf = 0; cf < 8; cf++) acc[cf] = (f32x4){0.f, 0.f, 0.f, 0.f};

#pragma unroll
    for (int ks = 0; ks < 2; ks++) {
        int rA = (wv << 4) + l15;
        int byteA = ((rA << 7) + (ks << 6) + (lhi << 4)) ^ ((rA & 7) << 4);
        bf16x8 a = *(const bf16x8*)(rbase + byteA);
#pragma unroll
        for (int cf = 0; cf < 8; cf++) {
            int rB = (cf << 4) + l15;
            int byteB = ((rB << 7) + (ks << 6) + (lhi << 4)) ^ ((rB & 7) << 4);
            bf16x8 b = *(const bf16x8*)(wbase + byteB);
            acc[cf] = __builtin_amdgcn_mfma_f32_16x16x32_bf16(a, b, acc[cf], 0, 0, 0);
        }
    }
    __syncthreads();
    for (int idx = tid; idx < 128 * 16; idx += 256) {
        int r = idx >> 4;
        int c0 = (idx & 15) << 3;
        float4 vA = *(const float4*)&W3[(size_t)r * 128 + c0];
        float4 vB = *(const float4*)&W3[(size_t)r * 128 + c0 + 4];
        unsigned short ua[8];
        ua[0] = f2bf(vA.x); ua[1] = f2bf(vA.y); ua[2] = f2bf(vA.z); ua[3] = f2bf(vA.w);
        ua[4] = f2bf(vB.x); ua[5] = f2bf(vB.y); ua[6] = f2bf(vB.z); ua[7] = f2bf(vB.w);
        int byte = ((r << 8) + ((idx & 15) << 4)) ^ ((r & 7) << 4);
        *(bf16x8*)(wbase + byte) = *(bf16x8*)ua;
    }
    __syncthreads();

#pragma unroll
    for (int ks = 0; ks < 4; ks++) {
        int rA = (wv << 4) + l15;
        int byteA = ((rA << 8) + (ks << 6) + (lhi << 4)) ^ ((rA & 7) << 4);
        bf16x8 a = *(const bf16x8*)(xbase + byteA);
#pragma unroll
        for (int cf = 0; cf < 8; cf++) {
            int rB = (cf << 4) + l15;
            int byteB = ((rB << 8) + (ks << 6) + (lhi << 4)) ^ ((rB & 7) << 4);
            bf16x8 b = *(const bf16x8*)(wbase + byteB);
            acc[cf] = __builtin_amdgcn_mfma_f32_16x16x32_bf16(a, b, acc[cf], 0, 0, 0);
        }
    }

#pragma unroll
    for (int cf = 0; cf < 8; cf++) {
        int col = (cf << 4) + l15;
#pragma unroll
        for (int j = 0; j < 4; j++) {
            int n = n0 + (wv << 4) + (lhi << 2) + j;
            if (n < N_NODES) out[(size_t)n * 128 + col] = acc[cf][j];
        }
    }
}

extern "C" void kernel_launch(void* const* d_in, const int* in_sizes, int n_in,
                              void* d_out, int out_size, void* d_ws, size_t ws_size,
                              hipStream_t stream) {
    const float* x    = (const float*)d_in[0];
    const float* w    = (const float*)d_in[1];
    const float* pf   = (const float*)d_in[2];
    const int*   head = (const int*)d_in[3];
    const int*   tail = (const int*)d_in[4];
    const int*   ind  = (const int*)d_in[5];
    const float* Wsc  = (const float*)d_in[6];
    const float* g1   = (const float*)d_in[7];
    const float* b1   = (const float*)d_in[8];
    const float* W1   = (const float*)d_in[9];
    const float* g2   = (const float*)d_in[10];
    const float* b2   = (const float*)d_in[11];
    const float* W2   = (const float*)d_in[12];
    const float* g3   = (const float*)d_in[13];
    const float* b3   = (const float*)d_in[14];
    const float* W3   = (const float*)d_in[15];
    float* out = (float*)d_out;

    char* p = (char*)d_ws;
    unsigned short* hs = (unsigned short*)p;  p += (size_t)N_NODES * 32 * 2;   // 6.4MB
    char* aggraw = p;                         p += (size_t)N_NODES * 128 * 4;  // 51.2MB
    unsigned short* agg_bf = (unsigned short*)aggraw;
    float*          agg_f  = (float*)aggraw;
    // hb16 (E x 16B = 25.6MB) aliases the upper half of aggraw: fully
    // consumed by sortGather before agg_bf (lower 25.6MB) is written.
    uint4* hb16 = (uint4*)(aggraw + (size_t)N_NODES * 128 * 2);
    float* jet1 = (float*)p;                  p += 1024 * 64 * 4;
    float* jet2 = (float*)p;                  p += 1024 * 128 * 4;
    float* jet3 = (float*)p;                  p += 1024 * 128 * 4;
    float* sc1 = (float*)p; p += 64 * 4;  float* sh1 = (float*)p; p += 64 * 4;
    float* sc2 = (float*)p; p += 128 * 4; float* sh2 = (float*)p; p += 128 * 4;
    float* sc3 = (float*)p; p += 128 * 4; float* sh3 = (float*)p; p += 128 * 4;
    int* cnt_e    = (int*)p; p += (size_t)N_NODES * 4;
    int* base_e   = (int*)p; p += (size_t)N_NODES * 4;
    int* cursor_e = (int*)p; p += (size_t)N_NODES * 4;
    int* part     = (int*)p; p += 1024 * 4;
    int* cntI     = (int*)p; p += 1024 * 4;
    int* baseI    = (int*)p; p += 1024 * 4;
    int* cursorI  = (int*)p; p += 1024 * 4;
    int* order    = (int*)p; p += (size_t)N_NODES * 4;
    int* eid      = (int*)p; p += (size_t)N_EDGES * 4;        // 6.4MB (tier2)
    size_t need_t2 = (size_t)(p - (char*)d_ws);
    int* bcnt  = (int*)p; p += NBUK * 4;
    int* bbase = (int*)p; p += NBUK * 4;
    int* bcur  = (int*)p; p += NBUK * 4;
    size_t need_t1 = (size_t)(p - (char*)d_ws);
    int tier = (ws_size >= need_t1) ? 1 : (ws_size >= need_t2) ? 2 : 3;

    // ---- indicator-CSR (atomic-free jets) ----
    hipMemsetAsync(cntI, 0, 1024 * sizeof(int), stream);
    countI_kernel<<<(N_NODES + 255) / 256, 256, 0, stream>>>(ind, cntI);
    scanB_kernel<<<1, 1024, 0, stream>>>(cntI, baseI, cursorI, 1024);
    scatterI_kernel<<<(N_NODES + 255) / 256, 256, 0, stream>>>(ind, cursorI, order);

    // ---- BN1 stats ----
    bucket_jet_kernel<64><<<1024, 256, 0, stream>>>(x, w, order, baseI, cntI, jet1);
    stats_kernel<64><<<64, 256, 0, stream>>>(jet1, g1, b1, sc1, sh1);

    // ---- layer1 (hs only, MFMA) ----
    fused1_kernel<<<(N_NODES + TILE1 - 1) / TILE1, 256, 0, stream>>>(
        x, w, sc1, sh1, W1, hs);

    // ---- edge message passing ----
    if (tier == 1) {
        hipMemsetAsync(bcnt, 0, NBUK * sizeof(int), stream);
        countB2_kernel<<<NBA, 1024, 0, stream>>>(head, bcnt);
        scanB_kernel<<<1, 1024, 0, stream>>>(bcnt, bbase, bcur, NBUK);
        binC16b_kernel<<<NBA, 1024, 0, stream>>>(head, tail, pf, bcur, hb16);
        sortGather_kernel<<<NBUK, 512, 0, stream>>>(bbase, bcnt, hb16, hs, agg_bf);
    } else if (tier == 2) {
        hipMemsetAsync(cnt_e, 0, N_NODES * sizeof(int), stream);
        count_head_kernel<<<(N_EDGES + 255) / 256, 256, 0, stream>>>(head, cnt_e);
        scanA_kernel<<<SNBLK, SCHUNK, 0, stream>>>(cnt_e, part, N_NODES);
        scanB_kernel<<<1, 1024, 0, stream>>>(part, part, nullptr, SNBLK);
        scanC_kernel<<<SNBLK, SCHUNK, 0, stream>>>(cnt_e, part, base_e, cursor_e, N_NODES);
        escatterE_kernel<<<(N_EDGES + 255) / 256, 256, 0, stream>>>(
            head, cursor_e, eid);
        gather2_kernel<<<(N_NODES + 3) / 4, 256, 0, stream>>>(
            base_e, cnt_e, eid, tail, pf, hs, agg_bf);
    }

    if (tier <= 2) {
        // ---- BN2 + layer2 (bf16 in-place) ----
        bucket_jet_bf128_kernel<<<1024, 256, 0, stream>>>(agg_bf, w, order, baseI, cntI, jet2);
        stats_kernel<128><<<128, 256, 0, stream>>>(jet2, g2, b2, sc2, sh2);
        fused2_kernel<1, 1><<<(N_NODES + TILE2 - 1) / TILE2, 256, 0, stream>>>(
            agg_bf, sc2, sh2, W2, agg_bf);
        // ---- BN3 + layer3 + shortcut (dual GEMM) ----
        bucket_jet_bf128_kernel<<<1024, 256, 0, stream>>>(agg_bf, w, order, baseI, cntI, jet3);
        stats_kernel<128><<<128, 256, 0, stream>>>(jet3, g3, b3, sc3, sh3);
        fused3_kernel<1><<<(N_NODES + TILE2 - 1) / TILE2, 256, 0, stream>>>(
            agg_bf, x, sc3, sh3, Wsc, W3, out);
    } else {
        // tier-3: f32 atomic fallback pipeline
        hipMemsetAsync(agg_f, 0, (size_t)N_NODES * 128 * sizeof(float), stream);
        edge_kernel<<<(int)(((long long)N_EDGES * 128) / 256), 256, 0, stream>>>(
            head, tail, pf, hs, agg_f);
        bucket_jet_kernel<128><<<1024, 256, 0, stream>>>(agg_f, w, order, baseI, cntI, jet2);
        stats_kernel<128><<<128, 256, 0, stream>>>(jet2, g2, b2, sc2, sh2);
        fused2_kernel<0, 0><<<(N_NODES + TILE2 - 1) / TILE2, 256, 0, stream>>>(
            agg_f, sc2, sh2, W2, agg_f);
        bucket_jet_kernel<128><<<1024, 256, 0, stream>>>(agg_f, w, order, baseI, cntI, jet3);
        stats_kernel<128><<<128, 256, 0, stream>>>(jet3, g3, b3, sc3, sh3);
        fused3_kernel<0><<<(N_NODES + TILE2 - 1) / TILE2, 256, 0, stream>>>(
            agg_f, x, sc3, sh3, Wsc, W3, out);
    }

    (void)in_sizes; (void)n_in; (void)out_size;
}

// Round 17
// 282.297 us; speedup vs baseline: 1.0321x; 1.0321x over previous
//
#include <hip/hip_runtime.h>

#define N_NODES 100000
#define N_EDGES 1600000
#define NB      1024
#define EPSF    1e-5f

#define SCHUNK 256
#define SNBLK ((N_NODES + SCHUNK - 1) / SCHUNK)   // 391

#define BUK_SH  7
#define NBUK    ((N_NODES + 127) >> 7)            // 782 buckets of 128 heads
#define EPB     6400
#define NBA     ((N_EDGES + EPB - 1) / EPB)       // 250 binning blocks
#define NCB     (NBUK * NBA)                      // 195,500 count-matrix entries
#define SNB2    ((NCB + SCHUNK - 1) / SCHUNK)     // 764 (<=1024 for scanB)
#define CAP     3072                              // LDS record cap per bucket

typedef float f32x4  __attribute__((ext_vector_type(4)));
typedef short bf16x8 __attribute__((ext_vector_type(8)));

__device__ __forceinline__ float bf2f(unsigned short u) {
    union { unsigned int i; float f; } v; v.i = ((unsigned int)u) << 16; return v.f;
}
__device__ __forceinline__ unsigned short f2bf(float f) {
    union { float ff; unsigned int i; } v; v.ff = f;
    unsigned int r = v.i + 0x7FFFu + ((v.i >> 16) & 1u);   // RNE
    return (unsigned short)(r >> 16);
}

// -------------- per-channel mean/var(ddof=1) -> scale/shift --------------
template<int C>
__global__ __launch_bounds__(256) void stats_kernel(const float* __restrict__ jet,
                                                    const float* __restrict__ g,
                                                    const float* __restrict__ b,
                                                    float* __restrict__ scale,
                                                    float* __restrict__ shift) {
    int c = blockIdx.x;
    int t = threadIdx.x;
    float s = 0.f, s2 = 0.f;
    for (int r = t; r < NB; r += 256) {
        float v = jet[r * C + c];
        s += v; s2 += v * v;
    }
    __shared__ float ls[256], ls2[256];
    ls[t] = s; ls2[t] = s2;
    __syncthreads();
    for (int ofs = 128; ofs > 0; ofs >>= 1) {
        if (t < ofs) { ls[t] += ls[t + ofs]; ls2[t] += ls2[t + ofs]; }
        __syncthreads();
    }
    if (t == 0) {
        float mean = ls[0] / (float)NB;
        float var  = (ls2[0] - (float)NB * mean * mean) / (float)(NB - 1);
        float sc   = g[c] / sqrtf(var + EPSF);
        scale[c] = sc;
        shift[c] = b[c] - mean * sc;
    }
}

// ---------------- count kernels ------------------------------------------
__global__ __launch_bounds__(256) void countI_kernel(const int* __restrict__ ind,
                                                     int* __restrict__ cntI) {
    int n = blockIdx.x * 256 + threadIdx.x;
    if (n < N_NODES) atomicAdd(&cntI[ind[n]], 1);
}

__global__ __launch_bounds__(256) void count_head_kernel(const int* __restrict__ head,
                                                         int* __restrict__ cnt) {
    int e = blockIdx.x * 256 + threadIdx.x;
    if (e < N_EDGES) atomicAdd(&cnt[head[e]], 1);
}

// per-(bucket,block) histogram, bucket-major output; 1024 threads
__global__ __launch_bounds__(1024) void countCB_kernel(const int* __restrict__ head,
                                                       int* __restrict__ cnt_cb) {
    __shared__ int h[NBUK];
    int tid = threadIdx.x;
    int blk = blockIdx.x;
    for (int i = tid; i < NBUK; i += 1024) h[i] = 0;
    __syncthreads();
    int e0 = blk * EPB;
    for (int k = tid; k < EPB; k += 1024) {
        int e = e0 + k;
        if (e < N_EDGES) atomicAdd(&h[head[e] >> BUK_SH], 1);
    }
    __syncthreads();
    for (int i = tid; i < NBUK; i += 1024) cnt_cb[i * NBA + blk] = h[i];
}

// ---------------- scans ---------------------------------------------------
__global__ __launch_bounds__(SCHUNK) void scanA_kernel(const int* __restrict__ cnt,
                                                       int* __restrict__ part, int n) {
    __shared__ int ls[SCHUNK];
    int t = threadIdx.x;
    int i = blockIdx.x * SCHUNK + t;
    ls[t] = (i < n) ? cnt[i] : 0;
    __syncthreads();
    for (int ofs = SCHUNK / 2; ofs > 0; ofs >>= 1) {
        if (t < ofs) ls[t] += ls[t + ofs];
        __syncthreads();
    }
    if (t == 0) part[blockIdx.x] = ls[0];
}

// single-block scan (n <= 1024); EXCLUSIVE prefix to out (and out2)
__global__ __launch_bounds__(1024) void scanB_kernel(const int* __restrict__ in,
                                                     int* __restrict__ out,
                                                     int* __restrict__ out2, int n) {
    __shared__ int ls[1024];
    int t = threadIdx.x;
    int v = (t < n) ? in[t] : 0;
    ls[t] = v;
    __syncthreads();
    for (int ofs = 1; ofs < 1024; ofs <<= 1) {
        int u = (t >= ofs) ? ls[t - ofs] : 0;
        __syncthreads();
        ls[t] += u;
        __syncthreads();
    }
    if (t < n) {
        int e = ls[t] - v;
        out[t] = e;
        if (out2) out2[t] = e;
    }
}

__global__ __launch_bounds__(SCHUNK) void scanC_kernel(const int* __restrict__ cnt,
                                                       const int* __restrict__ poff,
                                                       int* __restrict__ base,
                                                       int* __restrict__ cursor, int n) {
    __shared__ int ls[SCHUNK];
    int t = threadIdx.x;
    int i = blockIdx.x * SCHUNK + t;
    int v = (i < n) ? cnt[i] : 0;
    ls[t] = v;
    __syncthreads();
    for (int ofs = 1; ofs < SCHUNK; ofs <<= 1) {
        int u = (t >= ofs) ? ls[t - ofs] : 0;
        __syncthreads();
        ls[t] += u;
        __syncthreads();
    }
    if (i < n) {
        int bse = poff[blockIdx.x] + ls[t] - v;
        base[i] = bse;
        cursor[i] = bse;
    }
}

// ---- binC16: bin PAYLOAD records (AoS 16B) into bucket chunks -----------
// rec = {tail | h7<<21, pf01 bf16x2, pf23 bf16x2, 0}; one 16B write/edge
__global__ __launch_bounds__(1024) void binC16_kernel(const int* __restrict__ head,
                                                      const int* __restrict__ tail,
                                                      const float* __restrict__ pf,
                                                      const int* __restrict__ cbase,
                                                      uint4* __restrict__ hb16) {
    __shared__ int cur[NBUK];
    int tid = threadIdx.x;
    int blk = blockIdx.x;
    for (int i = tid; i < NBUK; i += 1024) cur[i] = cbase[i * NBA + blk];
    __syncthreads();
    int e0 = blk * EPB;
    for (int k = tid; k < EPB; k += 1024) {
        int e = e0 + k;
        if (e < N_EDGES) {
            int hd = head[e];
            int b = hd >> BUK_SH;
            int slot = atomicAdd(&cur[b], 1);
            float4 pv = ((const float4*)pf)[e];
            uint4 rec;
            rec.x = (unsigned)tail[e] | ((unsigned)(hd & 127) << 21);
            rec.y = (unsigned)f2bf(pv.x) | ((unsigned)f2bf(pv.y) << 16);
            rec.z = (unsigned)f2bf(pv.z) | ((unsigned)f2bf(pv.w) << 16);
            rec.w = 0u;
            hb16[slot] = rec;
        }
    }
}

// ---- sortGather: register-staged per-bucket CSR in LDS + fused gather ---
// One block per bucket. Records loaded ONCE into named registers; count,
// scan, scatter-to-LDS all from registers. Pass 3: 8 waves x 16 heads.
__global__ __launch_bounds__(512) void sortGather_kernel(const int* __restrict__ cbase,
                                                         const uint4* __restrict__ hb16,
                                                         const unsigned short* __restrict__ hs,
                                                         unsigned short* __restrict__ agg) {
    __shared__ int hcnt[128];
    __shared__ int hbase[128];
    __shared__ int hcur[128];
    __shared__ int tail_l[CAP];        // 12KB
    __shared__ unsigned pf_l[2 * CAP]; // 24KB
    int tid = threadIdx.x;
    int b = blockIdx.x;
    int lo = cbase[b * NBA];
    int hi = (b + 1 < NBUK) ? cbase[(b + 1) * NBA] : N_EDGES;
    int cnt = hi - lo;
    if (tid < 128) hcnt[tid] = 0;
    __syncthreads();

    int wv = tid >> 6, lane = tid & 63;
    int i = lane >> 1, half = lane & 1;

    if (cnt <= CAP) {
        // register-stage this thread's records (<= 6 at CAP=3072, 512 thr)
        uint4 r0, r1, r2, r3, r4, r5;
        int k0 = lo + tid;
        bool v0 = (k0 < hi),            v1 = (k0 + 512 < hi);
        bool v2 = (k0 + 1024 < hi),     v3 = (k0 + 1536 < hi);
        bool v4 = (k0 + 2048 < hi),     v5 = (k0 + 2560 < hi);
        if (v0) r0 = hb16[k0];
        if (v1) r1 = hb16[k0 + 512];
        if (v2) r2 = hb16[k0 + 1024];
        if (v3) r3 = hb16[k0 + 1536];
        if (v4) r4 = hb16[k0 + 2048];
        if (v5) r5 = hb16[k0 + 2560];
        if (v0) atomicAdd(&hcnt[r0.x >> 21], 1);
        if (v1) atomicAdd(&hcnt[r1.x >> 21], 1);
        if (v2) atomicAdd(&hcnt[r2.x >> 21], 1);
        if (v3) atomicAdd(&hcnt[r3.x >> 21], 1);
        if (v4) atomicAdd(&hcnt[r4.x >> 21], 1);
        if (v5) atomicAdd(&hcnt[r5.x >> 21], 1);
        __syncthreads();
        if (tid < 128) hbase[tid] = hcnt[tid];
        __syncthreads();
        for (int ofs = 1; ofs < 128; ofs <<= 1) {
            int v = (tid < 128 && tid >= ofs) ? hbase[tid - ofs] : 0;
            __syncthreads();
            if (tid < 128) hbase[tid] += v;
            __syncthreads();
        }
        if (tid < 128) {
            int bse = hbase[tid] - hcnt[tid];
            hbase[tid] = bse;
            hcur[tid] = bse;
        }
        __syncthreads();
        // scatter from registers into LDS
        if (v0) { int s = atomicAdd(&hcur[r0.x >> 21], 1); tail_l[s] = (int)(r0.x & 0xFFFFFu); pf_l[2*s] = r0.y; pf_l[2*s+1] = r0.z; }
        if (v1) { int s = atomicAdd(&hcur[r1.x >> 21], 1); tail_l[s] = (int)(r1.x & 0xFFFFFu); pf_l[2*s] = r1.y; pf_l[2*s+1] = r1.z; }
        if (v2) { int s = atomicAdd(&hcur[r2.x >> 21], 1); tail_l[s] = (int)(r2.x & 0xFFFFFu); pf_l[2*s] = r2.y; pf_l[2*s+1] = r2.z; }
        if (v3) { int s = atomicAdd(&hcur[r3.x >> 21], 1); tail_l[s] = (int)(r3.x & 0xFFFFFu); pf_l[2*s] = r3.y; pf_l[2*s+1] = r3.z; }
        if (v4) { int s = atomicAdd(&hcur[r4.x >> 21], 1); tail_l[s] = (int)(r4.x & 0xFFFFFu); pf_l[2*s] = r4.y; pf_l[2*s+1] = r4.z; }
        if (v5) { int s = atomicAdd(&hcur[r5.x >> 21], 1); tail_l[s] = (int)(r5.x & 0xFFFFFu); pf_l[2*s] = r5.y; pf_l[2*s+1] = r5.z; }
        __syncthreads();
        // pass 3: gather from LDS
        for (int j = 0; j < 16; j++) {
            int h7 = (wv << 4) + j;
            int n = (b << BUK_SH) + h7;
            if (n >= N_NODES) break;
            int s0 = hbase[h7], c = hcnt[h7];
            float a0 = 0.f, a1 = 0.f;
            int k = 0;
            for (; k + 4 <= c; k += 4) {
                int t0 = tail_l[s0 + k],     t1 = tail_l[s0 + k + 1];
                int t2 = tail_l[s0 + k + 2], t3 = tail_l[s0 + k + 3];
                unsigned u0 = pf_l[2 * (s0 + k) + half];
                unsigned u1 = pf_l[2 * (s0 + k + 1) + half];
                unsigned u2 = pf_l[2 * (s0 + k + 2) + half];
                unsigned u3 = pf_l[2 * (s0 + k + 3) + half];
                float h0 = bf2f(hs[(size_t)t0 * 32 + i]);
                float h1 = bf2f(hs[(size_t)t1 * 32 + i]);
                float h2 = bf2f(hs[(size_t)t2 * 32 + i]);
                float h3 = bf2f(hs[(size_t)t3 * 32 + i]);
                a0 += h0 * bf2f((unsigned short)(u0 & 0xFFFFu));
                a1 += h0 * bf2f((unsigned short)(u0 >> 16));
                a0 += h1 * bf2f((unsigned short)(u1 & 0xFFFFu));
                a1 += h1 * bf2f((unsigned short)(u1 >> 16));
                a0 += h2 * bf2f((unsigned short)(u2 & 0xFFFFu));
                a1 += h2 * bf2f((unsigned short)(u2 >> 16));
                a0 += h3 * bf2f((unsigned short)(u3 & 0xFFFFu));
                a1 += h3 * bf2f((unsigned short)(u3 >> 16));
            }
            for (; k < c; k++) {
                int t0 = tail_l[s0 + k];
                unsigned u0 = pf_l[2 * (s0 + k) + half];
                float h0 = bf2f(hs[(size_t)t0 * 32 + i]);
                a0 += h0 * bf2f((unsigned short)(u0 & 0xFFFFu));
                a1 += h0 * bf2f((unsigned short)(u0 >> 16));
            }
            unsigned pk = (unsigned)f2bf(a0) | ((unsigned)f2bf(a1) << 16);
            ((unsigned*)agg)[(size_t)n * 64 + lane] = pk;
        }
    } else {
        // overflow fallback: per-head redundant scan of the global window
        for (int j = 0; j < 16; j++) {
            int h7 = (wv << 4) + j;
            int n = (b << BUK_SH) + h7;
            if (n >= N_NODES) break;
            unsigned my = (unsigned)h7;
            float a0 = 0.f, a1 = 0.f;
            for (int k = lo; k < hi; k++) {
                uint4 rec = hb16[k];
                if ((rec.x >> 21) == my) {
                    unsigned u0 = (half == 0) ? rec.y : rec.z;
                    float h0 = bf2f(hs[(size_t)(rec.x & 0xFFFFFu) * 32 + i]);
                    a0 += h0 * bf2f((unsigned short)(u0 & 0xFFFFu));
                    a1 += h0 * bf2f((unsigned short)(u0 >> 16));
                }
            }
            unsigned pk = (unsigned)f2bf(a0) | ((unsigned)f2bf(a1) << 16);
            ((unsigned*)agg)[(size_t)n * 64 + lane] = pk;
        }
    }
}

// ---------------- legacy scatter (tier-2 fallback) -----------------------
__global__ __launch_bounds__(256) void escatterE_kernel(const int* __restrict__ head,
                                                        int* __restrict__ cursor,
                                                        int* __restrict__ eid) {
    int e = blockIdx.x * 256 + threadIdx.x;
    if (e >= N_EDGES) return;
    int slot = atomicAdd(&cursor[head[e]], 1);
    eid[slot] = e;
}

__global__ __launch_bounds__(256) void scatterI_kernel(const int* __restrict__ ind,
                                                       int* __restrict__ cursorI,
                                                       int* __restrict__ order) {
    int n = blockIdx.x * 256 + threadIdx.x;
    if (n < N_NODES) {
        int pos = atomicAdd(&cursorI[ind[n]], 1);
        order[pos] = n;
    }
}

// ---------- bucket jet (f32 input): jet[b,c] = sum x[n,c]*w[n] -----------
template<int C>
__global__ __launch_bounds__(256) void bucket_jet_kernel(const float* __restrict__ xx,
                                                         const float* __restrict__ w,
                                                         const int* __restrict__ order,
                                                         const int* __restrict__ baseI,
                                                         const int* __restrict__ cntI,
                                                         float* __restrict__ jet) {
    constexpr int G = 256 / C;
    __shared__ float red[256];
    int b = blockIdx.x;
    int g = threadIdx.x / C;
    int c = threadIdx.x % C;
    int s0 = baseI[b], m = cntI[b];
    float s = 0.f;
    for (int k = g; k < m; k += G) {
        int n = order[s0 + k];
        s += xx[(size_t)n * C + c] * w[n];
    }
    red[threadIdx.x] = s;
    __syncthreads();
    for (int half = G / 2; half > 0; half >>= 1) {
        if (g < half) red[g * C + c] += red[(g + half) * C + c];
        __syncthreads();
    }
    if (g == 0) jet[b * C + c] = red[c];
}

// ---------- bucket jet (bf16 input, C=128): uint-packed reads ------------
__global__ __launch_bounds__(256) void bucket_jet_bf128_kernel(const unsigned short* __restrict__ xx,
                                                               const float* __restrict__ w,
                                                               const int* __restrict__ order,
                                                               const int* __restrict__ baseI,
                                                               const int* __restrict__ cntI,
                                                               float* __restrict__ jet) {
    __shared__ float redA[256], redB[256];
    int b = blockIdx.x;
    int g  = threadIdx.x >> 6;     // 4 groups
    int c2 = threadIdx.x & 63;     // channel pair
    int s0 = baseI[b], m = cntI[b];
    float a0 = 0.f, a1 = 0.f;
    for (int k = g; k < m; k += 4) {
        int n = order[s0 + k];
        float wn = w[n];
        unsigned u = ((const unsigned*)xx)[(size_t)n * 64 + c2];
        a0 += bf2f((unsigned short)(u & 0xFFFFu)) * wn;
        a1 += bf2f((unsigned short)(u >> 16)) * wn;
    }
    redA[threadIdx.x] = a0; redB[threadIdx.x] = a1;
    __syncthreads();
    for (int half = 2; half > 0; half >>= 1) {
        if (g < half) {
            redA[g * 64 + c2] += redA[(g + half) * 64 + c2];
            redB[g * 64 + c2] += redB[(g + half) * 64 + c2];
        }
        __syncthreads();
    }
    if (g == 0) {
        jet[b * 128 + 2 * c2]     = redA[c2];
        jet[b * 128 + 2 * c2 + 1] = redB[c2];
    }
}

// --------- fused1 MFMA: hs = (relu(bn1(x)) @ W1^T) * w  (hs only) --------
#define TILE1 64
__global__ __launch_bounds__(256) void fused1_kernel(const float* __restrict__ x,
                                                     const float* __restrict__ w,
                                                     const float* __restrict__ scale,
                                                     const float* __restrict__ shift,
                                                     const float* __restrict__ W1,
                                                     unsigned short* __restrict__ hs) {
    __shared__ __align__(16) unsigned short xnb[TILE1 * 64];   // 8KB
    __shared__ __align__(16) unsigned short w1b[32 * 64];      // 4KB
    int tid = threadIdx.x;
    int n0  = blockIdx.x * TILE1;
    char* xnb_ = (char*)xnb; char* w1b_ = (char*)w1b;

    for (int idx = tid; idx < TILE1 * 8; idx += 256) {
        int r = idx >> 3, c0 = (idx & 7) << 3;
        int n = n0 + r;
        float4 vA = make_float4(0.f, 0.f, 0.f, 0.f), vB = vA;
        if (n < N_NODES) {
            vA = *(const float4*)&x[(size_t)n * 64 + c0];
            vB = *(const float4*)&x[(size_t)n * 64 + c0 + 4];
        }
        float4 scA = *(const float4*)&scale[c0], scB = *(const float4*)&scale[c0 + 4];
        float4 shA = *(const float4*)&shift[c0], shB = *(const float4*)&shift[c0 + 4];
        unsigned short na[8];
        na[0] = f2bf(fmaxf(fmaf(vA.x, scA.x, shA.x), 0.f));
        na[1] = f2bf(fmaxf(fmaf(vA.y, scA.y, shA.y), 0.f));
        na[2] = f2bf(fmaxf(fmaf(vA.z, scA.z, shA.z), 0.f));
        na[3] = f2bf(fmaxf(fmaf(vA.w, scA.w, shA.w), 0.f));
        na[4] = f2bf(fmaxf(fmaf(vB.x, scB.x, shB.x), 0.f));
        na[5] = f2bf(fmaxf(fmaf(vB.y, scB.y, shB.y), 0.f));
        na[6] = f2bf(fmaxf(fmaf(vB.z, scB.z, shB.z), 0.f));
        na[7] = f2bf(fmaxf(fmaf(vB.w, scB.w, shB.w), 0.f));
        int byte = ((r << 7) + ((idx & 7) << 4)) ^ ((r & 7) << 4);
        *(bf16x8*)(xnb_ + byte) = *(bf16x8*)na;
    }
    for (int idx = tid; idx < 32 * 8; idx += 256) {
        int r = idx >> 3, c0 = (idx & 7) << 3;
        float4 vA = *(const float4*)&W1[(size_t)r * 64 + c0];
        float4 vB = *(const float4*)&W1[(size_t)r * 64 + c0 + 4];
        unsigned short ua[8];
        ua[0] = f2bf(vA.x); ua[1] = f2bf(vA.y); ua[2] = f2bf(vA.z); ua[3] = f2bf(vA.w);
        ua[4] = f2bf(vB.x); ua[5] = f2bf(vB.y); ua[6] = f2bf(vB.z); ua[7] = f2bf(vB.w);
        int byte = ((r << 7) + ((idx & 7) << 4)) ^ ((r & 7) << 4);
        *(bf16x8*)(w1b_ + byte) = *(bf16x8*)ua;
    }
    __syncthreads();

    int wv   = tid >> 6;
    int lane = tid & 63;
    int l15  = lane & 15;
    int lhi  = lane >> 4;

    f32x4 acc[2];
    acc[0] = (f32x4){0.f, 0.f, 0.f, 0.f};
    acc[1] = (f32x4){0.f, 0.f, 0.f, 0.f};

#pragma unroll
    for (int ks = 0; ks < 2; ks++) {
        int rA = (wv << 4) + l15;
        int byteA = ((rA << 7) + (ks << 6) + (lhi << 4)) ^ ((rA & 7) << 4);
        bf16x8 a = *(const bf16x8*)(xnb_ + byteA);
#pragma unroll
        for (int cf = 0; cf < 2; cf++) {
            int rB = (cf << 4) + l15;
            int byteB = ((rB << 7) + (ks << 6) + (lhi << 4)) ^ ((rB & 7) << 4);
            bf16x8 b = *(const bf16x8*)(w1b_ + byteB);
            acc[cf] = __builtin_amdgcn_mfma_f32_16x16x32_bf16(a, b, acc[cf], 0, 0, 0);
        }
    }

#pragma unroll
    for (int cf = 0; cf < 2; cf++) {
        int co = (cf << 4) + l15;
#pragma unroll
        for (int j = 0; j < 4; j++) {
            int n = n0 + (wv << 4) + (lhi << 2) + j;
            if (n < N_NODES) hs[(size_t)n * 32 + co] = f2bf(acc[cf][j] * w[n]);
        }
    }
}

// ---------- gather (tier-2 only): wave per node via eid ------------------
__global__ __launch_bounds__(256) void gather2_kernel(const int* __restrict__ base,
                                                      const int* __restrict__ cnt,
                                                      const int* __restrict__ eid,
                                                      const int* __restrict__ tail,
                                                      const float* __restrict__ pf,
                                                      const unsigned short* __restrict__ hs,
                                                      unsigned short* __restrict__ agg) {
    int n = blockIdx.x * 4 + (threadIdx.x >> 6);
    if (n >= N_NODES) return;
    int lane = threadIdx.x & 63;
    int i = lane >> 1;
    int half = lane & 1;
    int s0 = base[n], c = cnt[n];
    float a0 = 0.f, a1 = 0.f;
    for (int k = 0; k < c; k++) {
        int e0 = eid[s0 + k];
        int t0 = tail[e0];
        float2 p0 = *(const float2*)&pf[(size_t)e0 * 4 + half * 2];
        float h0 = bf2f(hs[(size_t)t0 * 32 + i]);
        a0 += h0 * p0.x; a1 += h0 * p0.y;
    }
    unsigned pk = (unsigned)f2bf(a0) | ((unsigned)f2bf(a1) << 16);
    ((unsigned*)agg)[(size_t)n * 64 + lane] = pk;
}

// -------- legacy atomic edge scatter (tier-3, f32 agg) -------------------
__global__ __launch_bounds__(256) void edge_kernel(const int* __restrict__ head,
                                                   const int* __restrict__ tail,
                                                   const float* __restrict__ pf,
                                                   const unsigned short* __restrict__ hs,
                                                   float* __restrict__ agg) {
    long long tid = (long long)blockIdx.x * 256 + threadIdx.x;
    if (tid >= (long long)N_EDGES * 128) return;
    int e = (int)(tid >> 7);
    int j = (int)(tid & 127);
    int i = j >> 2, t = j & 3;
    float v = bf2f(hs[(size_t)tail[e] * 32 + i]) * pf[(size_t)e * 4 + t];
    atomicAdd(&agg[(size_t)head[e] * 128 + j], v);
}

// ------- fused2 MFMA: y = relu(bn(x)) @ W^T, in-place safe ---------------
#define TILE2 64
template<int INBF, int OUTBF>
__global__ __launch_bounds__(256) void fused2_kernel(const void* __restrict__ xin_,
                                                     const float* __restrict__ scale,
                                                     const float* __restrict__ shift,
                                                     const float* __restrict__ W,
                                                     void* __restrict__ yout_) {
    __shared__ __align__(16) unsigned short xnb[TILE2 * 128];   // 16KB
    __shared__ __align__(16) unsigned short wb[128 * 128];      // 32KB
    int tid = threadIdx.x;
    int n0  = blockIdx.x * TILE2;
    char* xbase = (char*)xnb;
    char* wbase = (char*)wb;

    for (int idx = tid; idx < TILE2 * 16; idx += 256) {
        int r = idx >> 4;
        int c0 = (idx & 15) << 3;
        int n = n0 + r;
        float f[8];
        if (n < N_NODES) {
            if (INBF) {
                const unsigned short* xu = (const unsigned short*)xin_;
                uint4 U = *(const uint4*)(xu + (size_t)n * 128 + c0);
                f[0] = bf2f((unsigned short)(U.x & 0xFFFFu)); f[1] = bf2f((unsigned short)(U.x >> 16));
                f[2] = bf2f((unsigned short)(U.y & 0xFFFFu)); f[3] = bf2f((unsigned short)(U.y >> 16));
                f[4] = bf2f((unsigned short)(U.z & 0xFFFFu)); f[5] = bf2f((unsigned short)(U.z >> 16));
                f[6] = bf2f((unsigned short)(U.w & 0xFFFFu)); f[7] = bf2f((unsigned short)(U.w >> 16));
            } else {
                const float* xf = (const float*)xin_;
                float4 vA = *(const float4*)&xf[(size_t)n * 128 + c0];
                float4 vB = *(const float4*)&xf[(size_t)n * 128 + c0 + 4];
                f[0] = vA.x; f[1] = vA.y; f[2] = vA.z; f[3] = vA.w;
                f[4] = vB.x; f[5] = vB.y; f[6] = vB.z; f[7] = vB.w;
            }
        } else {
#pragma unroll
            for (int q = 0; q < 8; q++) f[q] = 0.f;
        }
        unsigned short ua[8];
#pragma unroll
        for (int q = 0; q < 8; q++)
            ua[q] = f2bf(fmaxf(fmaf(f[q], scale[c0 + q], shift[c0 + q]), 0.f));
        int byte = ((r << 8) + ((idx & 15) << 4)) ^ ((r & 7) << 4);
        *(bf16x8*)(xbase + byte) = *(bf16x8*)ua;
    }
    for (int idx = tid; idx < 128 * 16; idx += 256) {
        int r = idx >> 4;
        int c0 = (idx & 15) << 3;
        float4 vA = *(const float4*)&W[(size_t)r * 128 + c0];
        float4 vB = *(const float4*)&W[(size_t)r * 128 + c0 + 4];
        unsigned short ua[8];
        ua[0] = f2bf(vA.x); ua[1] = f2bf(vA.y); ua[2] = f2bf(vA.z); ua[3] = f2bf(vA.w);
        ua[4] = f2bf(vB.x); ua[5] = f2bf(vB.y); ua[6] = f2bf(vB.z); ua[7] = f2bf(vB.w);
        int byte = ((r << 8) + ((idx & 15) << 4)) ^ ((r & 7) << 4);
        *(bf16x8*)(wbase + byte) = *(bf16x8*)ua;
    }
    __syncthreads();

    int wv   = tid >> 6;
    int lane = tid & 63;
    int l15  = lane & 15;
    int lhi  = lane >> 4;

    f32x4 acc[8];
#pragma unroll
    for (int cf = 0; cf < 8; cf++) acc[cf] = (f32x4){0.f, 0.f, 0.f, 0.f};

#pragma unroll
    for (int ks = 0; ks < 4; ks++) {
        int rA = (wv << 4) + l15;
        int byteA = ((rA << 8) + (ks << 6) + (lhi << 4)) ^ ((rA & 7) << 4);
        bf16x8 a = *(const bf16x8*)(xbase + byteA);
#pragma unroll
        for (int cf = 0; cf < 8; cf++) {
            int rB = (cf << 4) + l15;
            int byteB = ((rB << 8) + (ks << 6) + (lhi << 4)) ^ ((rB & 7) << 4);
            bf16x8 b = *(const bf16x8*)(wbase + byteB);
            acc[cf] = __builtin_amdgcn_mfma_f32_16x16x32_bf16(a, b, acc[cf], 0, 0, 0);
        }
    }

#pragma unroll
    for (int cf = 0; cf < 8; cf++) {
        int col = (cf << 4) + l15;
#pragma unroll
        for (int j = 0; j < 4; j++) {
            int n = n0 + (wv << 4) + (lhi << 2) + j;
            if (n < N_NODES) {
                float v = acc[cf][j];
                if (OUTBF) ((unsigned short*)yout_)[(size_t)n * 128 + col] = f2bf(v);
                else       ((float*)yout_)[(size_t)n * 128 + col] = v;
            }
        }
    }
}

// ------- fused3 dual-GEMM: out = relu(bn3(h2)) @ W3^T + x @ Wsc^T --------
template<int INBF>
__global__ __launch_bounds__(256) void fused3_kernel(const void* __restrict__ h2_,
                                                     const float* __restrict__ x,
                                                     const float* __restrict__ scale,
                                                     const float* __restrict__ shift,
                                                     const float* __restrict__ Wsc,
                                                     const float* __restrict__ W3,
                                                     float* __restrict__ out) {
    __shared__ __align__(16) unsigned short xnb[TILE2 * 128];   // 16KB (h2 normed)
    __shared__ __align__(16) unsigned short xrb[TILE2 * 64];    // 8KB  (x raw)
    __shared__ __align__(16) unsigned short wb[128 * 128];      // 32KB (Wsc then W3)
    int tid = threadIdx.x;
    int n0  = blockIdx.x * TILE2;
    char* xbase = (char*)xnb;
    char* rbase = (char*)xrb;
    char* wbase = (char*)wb;

    for (int idx = tid; idx < TILE2 * 16; idx += 256) {
        int r = idx >> 4;
        int c0 = (idx & 15) << 3;
        int n = n0 + r;
        float f[8];
        if (n < N_NODES) {
            if (INBF) {
                const unsigned short* xu = (const unsigned short*)h2_;
                uint4 U = *(const uint4*)(xu + (size_t)n * 128 + c0);
                f[0] = bf2f((unsigned short)(U.x & 0xFFFFu)); f[1] = bf2f((unsigned short)(U.x >> 16));
                f[2] = bf2f((unsigned short)(U.y & 0xFFFFu)); f[3] = bf2f((unsigned short)(U.y >> 16));
                f[4] = bf2f((unsigned short)(U.z & 0xFFFFu)); f[5] = bf2f((unsigned short)(U.z >> 16));
                f[6] = bf2f((unsigned short)(U.w & 0xFFFFu)); f[7] = bf2f((unsigned short)(U.w >> 16));
            } else {
                const float* xf = (const float*)h2_;
                float4 vA = *(const float4*)&xf[(size_t)n * 128 + c0];
                float4 vB = *(const float4*)&xf[(size_t)n * 128 + c0 + 4];
                f[0] = vA.x; f[1] = vA.y; f[2] = vA.z; f[3] = vA.w;
                f[4] = vB.x; f[5] = vB.y; f[6] = vB.z; f[7] = vB.w;
            }
        } else {
#pragma unroll
            for (int q = 0; q < 8; q++) f[q] = 0.f;
        }
        unsigned short ua[8];
#pragma unroll
        for (int q = 0; q < 8; q++)
            ua[q] = f2bf(fmaxf(fmaf(f[q], scale[c0 + q], shift[c0 + q]), 0.f));
        int byte = ((r << 8) + ((idx & 15) << 4)) ^ ((r & 7) << 4);
        *(bf16x8*)(xbase + byte) = *(bf16x8*)ua;
    }
    for (int idx = tid; idx < TILE2 * 8; idx += 256) {
        int r = idx >> 3, c0 = (idx & 7) << 3;
        int n = n0 + r;
        float4 vA = make_float4(0.f, 0.f, 0.f, 0.f), vB = vA;
        if (n < N_NODES) {
            vA = *(const float4*)&x[(size_t)n * 64 + c0];
            vB = *(const float4*)&x[(size_t)n * 64 + c0 + 4];
        }
        unsigned short ua[8];
        ua[0] = f2bf(vA.x); ua[1] = f2bf(vA.y); ua[2] = f2bf(vA.z); ua[3] = f2bf(vA.w);
        ua[4] = f2bf(vB.x); ua[5] = f2bf(vB.y); ua[6] = f2bf(vB.z); ua[7] = f2bf(vB.w);
        int byte = ((r << 7) + ((idx & 7) << 4)) ^ ((r & 7) << 4);
        *(bf16x8*)(rbase + byte) = *(bf16x8*)ua;
    }
    for (int idx = tid; idx < 128 * 8; idx += 256) {
        int r = idx >> 3, c0 = (idx & 7) << 3;
        float4 vA = *(const float4*)&Wsc[(size_t)r * 64 + c0];
        float4 vB = *(const float4*)&Wsc[(size_t)r * 64 + c0 + 4];
        unsigned short ua[8];
        ua[0] = f2bf(vA.x); ua[1] = f2bf(vA.y); ua[2] = f2bf(vA.z); ua[3] = f2bf(vA.w);
        ua[4] = f2bf(vB.x); ua[5] = f2bf(vB.y); ua[6] = f2bf(vB.z); ua[7] = f2bf(vB.w);
        int byte = ((r << 7) + ((idx & 7) << 4)) ^ ((r & 7) << 4);
        *(bf16x8*)(wbase + byte) = *(bf16x8*)ua;
    }
    __syncthreads();

    int wv   = tid >> 6;
    int lane = tid & 63;
    int l15  = lane & 15;
    int lhi  = lane >> 4;

    f32x4 acc[8];
#pragma unroll
    for (int cf = 0; cf < 8; cf++) acc[cf] = (f32x4){0.f, 0.f, 0.f, 0.f};

#pragma unroll
    for (int ks = 0; ks < 2; ks++) {
        int rA = (wv << 4) + l15;
        int byteA = ((rA << 7) + (ks << 6) + (lhi << 4)) ^ ((rA & 7) << 4);
        bf16x8 a = *(const bf16x8*)(rbase + byteA);
#pragma unroll
        for (int cf = 0; cf < 8; cf++) {
            int rB = (cf << 4) + l15;
            int byteB = ((rB << 7) + (ks << 6) + (lhi << 4)) ^ ((rB & 7) << 4);
            bf16x8 b = *(const bf16x8*)(wbase + byteB);
            acc[cf] = __builtin_amdgcn_mfma_f32_16x16x32_bf16(a, b, acc[cf], 0, 0, 0);
        }
    }
    __syncthreads();
    for (int idx = tid; idx < 128 * 16; idx += 256) {
        int r = idx >> 4;
        int c0 = (idx & 15) << 3;
        float4 vA = *(const float4*)&W3[(size_t)r * 128 + c0];
        float4 vB = *(const float4*)&W3[(size_t)r * 128 + c0 + 4];
        unsigned short ua[8];
        ua[0] = f2bf(vA.x); ua[1] = f2bf(vA.y); ua[2] = f2bf(vA.z); ua[3] = f2bf(vA.w);
        ua[4] = f2bf(vB.x); ua[5] = f2bf(vB.y); ua[6] = f2bf(vB.z); ua[7] = f2bf(vB.w);
        int byte = ((r << 8) + ((idx & 15) << 4)) ^ ((r & 7) << 4);
        *(bf16x8*)(wbase + byte) = *(bf16x8*)ua;
    }
    __syncthreads();

#pragma unroll
    for (int ks = 0; ks < 4; ks++) {
        int rA = (wv << 4) + l15;
        int byteA = ((rA << 8) + (ks << 6) + (lhi << 4)) ^ ((rA & 7) << 4);
        bf16x8 a = *(const bf16x8*)(xbase + byteA);
#pragma unroll
        for (int cf = 0; cf < 8; cf++) {
            int rB = (cf << 4) + l15;
            int byteB = ((rB << 8) + (ks << 6) + (lhi << 4)) ^ ((rB & 7) << 4);
            bf16x8 b = *(const bf16x8*)(wbase + byteB);
            acc[cf] = __builtin_amdgcn_mfma_f32_16x16x32_bf16(a, b, acc[cf], 0, 0, 0);
        }
    }

#pragma unroll
    for (int cf = 0; cf < 8; cf++) {
        int col = (cf << 4) + l15;
#pragma unroll
        for (int j = 0; j < 4; j++) {
            int n = n0 + (wv << 4) + (lhi << 2) + j;
            if (n < N_NODES) out[(size_t)n * 128 + col] = acc[cf][j];
        }
    }
}

extern "C" void kernel_launch(void* const* d_in, const int* in_sizes, int n_in,
                              void* d_out, int out_size, void* d_ws, size_t ws_size,
                              hipStream_t stream) {
    const float* x    = (const float*)d_in[0];
    const float* w    = (const float*)d_in[1];
    const float* pf   = (const float*)d_in[2];
    const int*   head = (const int*)d_in[3];
    const int*   tail = (const int*)d_in[4];
    const int*   ind  = (const int*)d_in[5];
    const float* Wsc  = (const float*)d_in[6];
    const float* g1   = (const float*)d_in[7];
    const float* b1   = (const float*)d_in[8];
    const float* W1   = (const float*)d_in[9];
    const float* g2   = (const float*)d_in[10];
    const float* b2   = (const float*)d_in[11];
    const float* W2   = (const float*)d_in[12];
    const float* g3   = (const float*)d_in[13];
    const float* b3   = (const float*)d_in[14];
    const float* W3   = (const float*)d_in[15];
    float* out = (float*)d_out;

    char* p = (char*)d_ws;
    unsigned short* hs = (unsigned short*)p;  p += (size_t)N_NODES * 32 * 2;   // 6.4MB
    char* aggraw = p;                         p += (size_t)N_NODES * 128 * 4;  // 51.2MB
    unsigned short* agg_bf = (unsigned short*)aggraw;
    float*          agg_f  = (float*)aggraw;
    // hb16 (E x 16B = 25.6MB) aliases the upper half of aggraw: fully
    // consumed by sortGather before agg_bf (lower 25.6MB) is written.
    uint4* hb16 = (uint4*)(aggraw + (size_t)N_NODES * 128 * 2);
    float* jet1 = (float*)p;                  p += 1024 * 64 * 4;
    float* jet2 = (float*)p;                  p += 1024 * 128 * 4;
    float* jet3 = (float*)p;                  p += 1024 * 128 * 4;
    float* sc1 = (float*)p; p += 64 * 4;  float* sh1 = (float*)p; p += 64 * 4;
    float* sc2 = (float*)p; p += 128 * 4; float* sh2 = (float*)p; p += 128 * 4;
    float* sc3 = (float*)p; p += 128 * 4; float* sh3 = (float*)p; p += 128 * 4;
    int* cnt_e    = (int*)p; p += (size_t)N_NODES * 4;
    int* base_e   = (int*)p; p += (size_t)N_NODES * 4;
    int* cursor_e = (int*)p; p += (size_t)N_NODES * 4;
    int* part     = (int*)p; p += 1024 * 4;
    int* cntI     = (int*)p; p += 1024 * 4;
    int* baseI    = (int*)p; p += 1024 * 4;
    int* cursorI  = (int*)p; p += 1024 * 4;
    int* order    = (int*)p; p += (size_t)N_NODES * 4;
    int* eid      = (int*)p; p += (size_t)N_EDGES * 4;        // 6.4MB (tier2)
    size_t need_t2 = (size_t)(p - (char*)d_ws);
    int* cnt_cb   = (int*)p; p += (size_t)NCB * 4;            // 782KB
    int* cbase    = (int*)p; p += (size_t)NCB * 4;
    int* ccur     = (int*)p; p += (size_t)NCB * 4;
    size_t need_t1 = (size_t)(p - (char*)d_ws);
    int tier = (ws_size >= need_t1) ? 1 : (ws_size >= need_t2) ? 2 : 3;

    // ---- indicator-CSR (atomic-free jets) ----
    hipMemsetAsync(cntI, 0, 1024 * sizeof(int), stream);
    countI_kernel<<<(N_NODES + 255) / 256, 256, 0, stream>>>(ind, cntI);
    scanB_kernel<<<1, 1024, 0, stream>>>(cntI, baseI, cursorI, 1024);
    scatterI_kernel<<<(N_NODES + 255) / 256, 256, 0, stream>>>(ind, cursorI, order);

    // ---- BN1 stats ----
    bucket_jet_kernel<64><<<1024, 256, 0, stream>>>(x, w, order, baseI, cntI, jet1);
    stats_kernel<64><<<64, 256, 0, stream>>>(jet1, g1, b1, sc1, sh1);

    // ---- layer1 (hs only, MFMA) ----
    fused1_kernel<<<(N_NODES + TILE1 - 1) / TILE1, 256, 0, stream>>>(
        x, w, sc1, sh1, W1, hs);

    // ---- edge message passing ----
    if (tier == 1) {
        countCB_kernel<<<NBA, 1024, 0, stream>>>(head, cnt_cb);
        scanA_kernel<<<SNB2, SCHUNK, 0, stream>>>(cnt_cb, part, NCB);
        scanB_kernel<<<1, 1024, 0, stream>>>(part, part, nullptr, SNB2);
        scanC_kernel<<<SNB2, SCHUNK, 0, stream>>>(cnt_cb, part, cbase, ccur, NCB);
        binC16_kernel<<<NBA, 1024, 0, stream>>>(head, tail, pf, cbase, hb16);
        sortGather_kernel<<<NBUK, 512, 0, stream>>>(cbase, hb16, hs, agg_bf);
    } else if (tier == 2) {
        hipMemsetAsync(cnt_e, 0, N_NODES * sizeof(int), stream);
        count_head_kernel<<<(N_EDGES + 255) / 256, 256, 0, stream>>>(head, cnt_e);
        scanA_kernel<<<SNBLK, SCHUNK, 0, stream>>>(cnt_e, part, N_NODES);
        scanB_kernel<<<1, 1024, 0, stream>>>(part, part, nullptr, SNBLK);
        scanC_kernel<<<SNBLK, SCHUNK, 0, stream>>>(cnt_e, part, base_e, cursor_e, N_NODES);
        escatterE_kernel<<<(N_EDGES + 255) / 256, 256, 0, stream>>>(
            head, cursor_e, eid);
        gather2_kernel<<<(N_NODES + 3) / 4, 256, 0, stream>>>(
            base_e, cnt_e, eid, tail, pf, hs, agg_bf);
    }

    if (tier <= 2) {
        // ---- BN2 + layer2 (bf16 in-place) ----
        bucket_jet_bf128_kernel<<<1024, 256, 0, stream>>>(agg_bf, w, order, baseI, cntI, jet2);
        stats_kernel<128><<<128, 256, 0, stream>>>(jet2, g2, b2, sc2, sh2);
        fused2_kernel<1, 1><<<(N_NODES + TILE2 - 1) / TILE2, 256, 0, stream>>>(
            agg_bf, sc2, sh2, W2, agg_bf);
        // ---- BN3 + layer3 + shortcut (dual GEMM) ----
        bucket_jet_bf128_kernel<<<1024, 256, 0, stream>>>(agg_bf, w, order, baseI, cntI, jet3);
        stats_kernel<128><<<128, 256, 0, stream>>>(jet3, g3, b3, sc3, sh3);
        fused3_kernel<1><<<(N_NODES + TILE2 - 1) / TILE2, 256, 0, stream>>>(
            agg_bf, x, sc3, sh3, Wsc, W3, out);
    } else {
        // tier-3: f32 atomic fallback pipeline
        hipMemsetAsync(agg_f, 0, (size_t)N_NODES * 128 * sizeof(float), stream);
        edge_kernel<<<(int)(((long long)N_EDGES * 128) / 256), 256, 0, stream>>>(
            head, tail, pf, hs, agg_f);
        bucket_jet_kernel<128><<<1024, 256, 0, stream>>>(agg_f, w, order, baseI, cntI, jet2);
        stats_kernel<128><<<128, 256, 0, stream>>>(jet2, g2, b2, sc2, sh2);
        fused2_kernel<0, 0><<<(N_NODES + TILE2 - 1) / TILE2, 256, 0, stream>>>(
            agg_f, sc2, sh2, W2, agg_f);
        bucket_jet_kernel<128><<<1024, 256, 0, stream>>>(agg_f, w, order, baseI, cntI, jet3);
        stats_kernel<128><<<128, 256, 0, stream>>>(jet3, g3, b3, sc3, sh3);
        fused3_kernel<0><<<(N_NODES + TILE2 - 1) / TILE2, 256, 0, stream>>>(
            agg_f, x, sc3, sh3, Wsc, W3, out);
    }

    (void)in_sizes; (void)n_in; (void)out_size;
}